// Round 1
// baseline (3040.641 us; speedup 1.0000x reference)
//
#include <hip/hip_runtime.h>
#include <math.h>

// Dims (fixed by problem)
#define VOCAB 10000
#define EMBED 256
#define ENC   2048
#define DEC   512
#define ATT   512
#define BATCH 64
#define P     49
#define T     30
#define G4    2048   // 4*DEC
#define KCAT1 2560   // ENC + DEC
#define KCAT2 1024   // DEC + DEC

__device__ __forceinline__ float sigf(float x) { return 1.f / (1.f + expf(-x)); }

// ---------------------------------------------------------------------------
// Generic fp32 GEMM: C[M,N] = A[M,K] @ B[N,K]^T + bias[N].  M % 64 == 0.
// block 256 thr, tile 64x64, BK=16, 4x4 micro-tile per thread.
// ---------------------------------------------------------------------------
__global__ __launch_bounds__(256) void gemm64(
    const float* __restrict__ A, int lda,
    const float* __restrict__ B, int ldb,
    float* __restrict__ C, int ldc,
    const float* __restrict__ bias,
    int N, int K)
{
    __shared__ float As[16][68];
    __shared__ float Bs[16][68];
    const int bn = blockIdx.x * 64;
    const int bm = blockIdx.y * 64;
    const int tid = threadIdx.x;
    const int tx = tid & 15, ty = tid >> 4;
    const int lk = tid & 15, lm = tid >> 4;

    float acc[4][4];
#pragma unroll
    for (int i = 0; i < 4; ++i)
#pragma unroll
        for (int j = 0; j < 4; ++j) {
            int gn = bn + tx * 4 + j;
            acc[i][j] = (bias && gn < N) ? bias[gn] : 0.f;
        }

    for (int k0 = 0; k0 < K; k0 += 16) {
#pragma unroll
        for (int r = 0; r < 4; ++r) {
            As[lk][lm + r * 16] = A[(size_t)(bm + lm + r * 16) * lda + k0 + lk];
            int gn = bn + lm + r * 16;
            Bs[lk][lm + r * 16] = (gn < N) ? B[(size_t)gn * ldb + k0 + lk] : 0.f;
        }
        __syncthreads();
#pragma unroll
        for (int kk = 0; kk < 16; ++kk) {
            float4 av = *(const float4*)&As[kk][ty * 4];
            float4 bv = *(const float4*)&Bs[kk][tx * 4];
            float ar[4] = {av.x, av.y, av.z, av.w};
            float br[4] = {bv.x, bv.y, bv.z, bv.w};
#pragma unroll
            for (int i = 0; i < 4; ++i)
#pragma unroll
                for (int j = 0; j < 4; ++j) acc[i][j] += ar[i] * br[j];
        }
        __syncthreads();
    }
#pragma unroll
    for (int i = 0; i < 4; ++i) {
        int gm = bm + ty * 4 + i;
#pragma unroll
        for (int j = 0; j < 4; ++j) {
            int gn = bn + tx * 4 + j;
            if (gn < N) C[(size_t)gm * ldc + gn] = acc[i][j];
        }
    }
}

// ---------------------------------------------------------------------------
// Split-K GEMM for the per-step skinny (M=64) gate GEMMs.
// grid = (N/64, KS). Writes partials P[ks][64][N]. No bias, no guards (N%64==0).
// ---------------------------------------------------------------------------
__global__ __launch_bounds__(256) void gemm64_splitk(
    const float* __restrict__ A, int lda,
    const float* __restrict__ B, int ldb,
    float* __restrict__ Part, int N, int Kc)
{
    __shared__ float As[16][68];
    __shared__ float Bs[16][68];
    const int bn = blockIdx.x * 64;
    const int kbase = blockIdx.y * Kc;
    const int tid = threadIdx.x;
    const int tx = tid & 15, ty = tid >> 4;
    const int lk = tid & 15, lm = tid >> 4;

    float acc[4][4];
#pragma unroll
    for (int i = 0; i < 4; ++i)
#pragma unroll
        for (int j = 0; j < 4; ++j) acc[i][j] = 0.f;

    for (int k0 = kbase; k0 < kbase + Kc; k0 += 16) {
#pragma unroll
        for (int r = 0; r < 4; ++r) {
            As[lk][lm + r * 16] = A[(size_t)(lm + r * 16) * lda + k0 + lk];
            Bs[lk][lm + r * 16] = B[(size_t)(bn + lm + r * 16) * ldb + k0 + lk];
        }
        __syncthreads();
#pragma unroll
        for (int kk = 0; kk < 16; ++kk) {
            float4 av = *(const float4*)&As[kk][ty * 4];
            float4 bv = *(const float4*)&Bs[kk][tx * 4];
            float ar[4] = {av.x, av.y, av.z, av.w};
            float br[4] = {bv.x, bv.y, bv.z, bv.w};
#pragma unroll
            for (int i = 0; i < 4; ++i)
#pragma unroll
                for (int j = 0; j < 4; ++j) acc[i][j] += ar[i] * br[j];
        }
        __syncthreads();
    }
    float* Cp = Part + (size_t)blockIdx.y * 64 * N;
#pragma unroll
    for (int i = 0; i < 4; ++i) {
        int gm = ty * 4 + i;
#pragma unroll
        for (int j = 0; j < 4; ++j) Cp[(size_t)gm * N + bn + tx * 4 + j] = acc[i][j];
    }
}

// ---------------------------------------------------------------------------
// Fused attention: per-batch block computes h2W2 (+b2), tanh-score dot V (+bV),
// softmax over P, and ctx = sum_p w*features. Writes ctx into Xcat1[:, 0:ENC].
// grid 64, 512 threads.
// ---------------------------------------------------------------------------
__global__ __launch_bounds__(512) void attn_fused(
    const float* __restrict__ Xcat2,    // h2 at col offset DEC, row stride KCAT2
    const float* __restrict__ W2t,      // [DEC][ATT] (transposed W2)
    const float* __restrict__ b2,
    const float* __restrict__ fW1,      // [B*P][ATT]
    const float* __restrict__ V,
    const float* __restrict__ bV,
    const float* __restrict__ features, // [B*P][ENC]
    float* __restrict__ Xcat1)          // ctx target, row stride KCAT1
{
    const int b = blockIdx.x;
    const int tid = threadIdx.x;
    __shared__ float h2s[DEC];
    __shared__ float hw[ATT];
    __shared__ float sc[64];
    __shared__ float wn[64];
    __shared__ float part[P][17];

    h2s[tid] = Xcat2[b * KCAT2 + DEC + tid];
    __syncthreads();

    // h2 @ W2^T + b2  (column a = tid, coalesced over W2t rows)
    {
        const float* wp = W2t + tid;
        float a0 = 0.f, a1 = 0.f, a2 = 0.f, a3 = 0.f;
        for (int d = 0; d < DEC; d += 4) {
            a0 += h2s[d + 0] * wp[(d + 0) * ATT];
            a1 += h2s[d + 1] * wp[(d + 1) * ATT];
            a2 += h2s[d + 2] * wp[(d + 2) * ATT];
            a3 += h2s[d + 3] * wp[(d + 3) * ATT];
        }
        hw[tid] = a0 + a1 + a2 + a3 + b2[tid];
    }
    __syncthreads();

    // scores: part[p][g] = sum over a in [g*32, g*32+32) of tanh(fW1+hw)*V
    {
        const int g = tid & 15, prow = tid >> 4;
#pragma unroll
        for (int r = 0; r < 2; ++r) {
            int p = prow + r * 32;
            if (p < P) {
                const float* fp = fW1 + (size_t)(b * P + p) * ATT + g * 32;
                float s = 0.f;
#pragma unroll 8
                for (int i = 0; i < 32; ++i)
                    s += tanhf(fp[i] + hw[g * 32 + i]) * V[g * 32 + i];
                part[p][g] = s;
            }
        }
    }
    __syncthreads();
    if (tid < P) {
        float s = 0.f;
#pragma unroll
        for (int g = 0; g < 16; ++g) s += part[tid][g];
        sc[tid] = s + bV[0];
    }
    __syncthreads();
    // softmax over P (redundant per-thread max/sum; LDS broadcast reads)
    float m = -1e30f;
    for (int p = 0; p < P; ++p) m = fmaxf(m, sc[p]);
    float ssum = 0.f;
    for (int p = 0; p < P; ++p) ssum += expf(sc[p] - m);
    if (tid < P) wn[tid] = expf(sc[tid] - m) / ssum;
    __syncthreads();

    // ctx[e] = sum_p wn[p] * features[b,p,e]
    for (int e = tid; e < ENC; e += 512) {
        float acc = 0.f;
        const float* fp = features + (size_t)b * P * ENC + e;
        for (int p = 0; p < P; ++p) acc += wn[p] * fp[(size_t)p * ENC];
        Xcat1[b * KCAT1 + e] = acc;
    }
}

// ---------------------------------------------------------------------------
// LSTM pointwise + split-K reduce. gates[b][j] = Cinit[b*ldci + j] + sum_ks P.
// ldci==0 broadcasts a bias vector. Writes h to two destinations.
// grid 128x256 (B*DEC threads).
// ---------------------------------------------------------------------------
__global__ __launch_bounds__(256) void lstm_point_reduce(
    const float* __restrict__ Part, int KS,
    const float* __restrict__ Cinit, int ldci,
    float* __restrict__ c,
    float* __restrict__ hA, int sA,
    float* __restrict__ hB, int sB)
{
    const int idx = blockIdx.x * 256 + threadIdx.x;  // < B*DEC
    const int b = idx >> 9, d = idx & 511;
    const int cb = b * ldci;
    float gi = Cinit[cb + d];
    float gf = Cinit[cb + DEC + d];
    float gg = Cinit[cb + 2 * DEC + d];
    float go = Cinit[cb + 3 * DEC + d];
    const float* p = Part + b * G4;
    for (int ks = 0; ks < KS; ++ks, p += BATCH * G4) {
        gi += p[d]; gf += p[DEC + d]; gg += p[2 * DEC + d]; go += p[3 * DEC + d];
    }
    float cn = sigf(gf) * c[idx] + sigf(gi) * tanhf(gg);
    c[idx] = cn;
    float h = sigf(go) * tanhf(cn);
    hA[b * sA + d] = h;
    hB[b * sB + d] = h;
}

// ---------------------------------------------------------------------------
// One-time prep kernels
// ---------------------------------------------------------------------------
__global__ void build_aux(const float* __restrict__ bih1, const float* __restrict__ bhh1,
                          float* __restrict__ bsum1,
                          const float* __restrict__ bih2, const float* __restrict__ bhh2,
                          float* __restrict__ bsum2,
                          const float* __restrict__ W2, float* __restrict__ W2t)
{
    int idx = blockIdx.x * 256 + threadIdx.x;
    if (idx < G4) { bsum1[idx] = bih1[idx] + bhh1[idx]; bsum2[idx] = bih2[idx] + bhh2[idx]; }
    for (int i = idx; i < ATT * DEC; i += gridDim.x * 256) {
        int a = i >> 9, d = i & 511;
        W2t[d * ATT + a] = W2[i];
    }
}

__global__ void build_wcat(const float* __restrict__ Wih1, const float* __restrict__ Whh1,
                           float* __restrict__ Wcat1,
                           const float* __restrict__ Wih2, const float* __restrict__ Whh2,
                           float* __restrict__ Wcat2)
{
    int idx = blockIdx.x * 256 + threadIdx.x;
    int stride = gridDim.x * 256;
    for (int i = idx; i < G4 * KCAT1; i += stride) {
        int j = i / KCAT1, cc = i - j * KCAT1;
        Wcat1[i] = (cc < ENC) ? Wih1[(size_t)j * (EMBED + ENC) + EMBED + cc]
                              : Whh1[(size_t)j * DEC + (cc - ENC)];
    }
    for (int i = idx; i < G4 * KCAT2; i += stride) {
        int j = i >> 10, cc = i & 1023;
        Wcat2[i] = (cc < DEC) ? Wih2[(size_t)j * DEC + cc]
                              : Whh2[(size_t)j * DEC + (cc - DEC)];
    }
}

__global__ void gather_emb(const int* __restrict__ caps, const float* __restrict__ emb,
                           float* __restrict__ xg)
{
    int idx = blockIdx.x * 256 + threadIdx.x;  // < T*B*EMBED
    int row = idx >> 8, e = idx & 255;
    int t = row >> 6, b = row & 63;            // row = t*64 + b
    int cap = caps[b * T + t];
    xg[idx] = emb[(size_t)cap * EMBED + e];
}

// ---------------------------------------------------------------------------
extern "C" void kernel_launch(void* const* d_in, const int* in_sizes, int n_in,
                              void* d_out, int out_size, void* d_ws, size_t ws_size,
                              hipStream_t stream)
{
    const float* features = (const float*)d_in[0];
    const int*   captions = (const int*)d_in[1];
    const float* emb   = (const float*)d_in[2];
    const float* W1    = (const float*)d_in[3];
    const float* b1    = (const float*)d_in[4];
    const float* W2    = (const float*)d_in[5];
    const float* b2    = (const float*)d_in[6];
    const float* V     = (const float*)d_in[7];
    const float* bV    = (const float*)d_in[8];
    const float* W_ih1 = (const float*)d_in[9];
    const float* W_hh1 = (const float*)d_in[10];
    const float* b_ih1 = (const float*)d_in[11];
    const float* b_hh1 = (const float*)d_in[12];
    const float* W_ih2 = (const float*)d_in[13];
    const float* W_hh2 = (const float*)d_in[14];
    const float* b_ih2 = (const float*)d_in[15];
    const float* b_hh2 = (const float*)d_in[16];
    const float* fc_W  = (const float*)d_in[17];
    const float* fc_b  = (const float*)d_in[18];
    float* out = (float*)d_out;

    char* ws = (char*)d_ws;
    size_t off = 0;
    auto alloc = [&](size_t nfloats) {
        float* p = (float*)(ws + off);
        off = (off + nfloats * 4 + 255) & ~(size_t)255;
        return p;
    };
    float* W2t   = alloc((size_t)ATT * DEC);          // 1 MB
    float* Wcat1 = alloc((size_t)G4 * KCAT1);         // 21 MB
    float* Wcat2 = alloc((size_t)G4 * KCAT2);         // 8.4 MB
    float* bsum1 = alloc(G4);
    float* bsum2 = alloc(G4);
    float* xg    = alloc((size_t)T * BATCH * EMBED);  // 2 MB
    float* fW1   = alloc((size_t)BATCH * P * ATT);    // 6.4 MB
    float* xembb = alloc((size_t)T * BATCH * G4);     // 15.7 MB
    float* Partb = alloc((size_t)16 * BATCH * G4);    // 8 MB
    float* Xcat1 = alloc((size_t)BATCH * KCAT1);      // [ctx | h1]
    float* Xcat2 = alloc((size_t)BATCH * KCAT2);      // [h1n | h2]
    float* c1    = alloc((size_t)BATCH * DEC);
    float* c2    = alloc((size_t)BATCH * DEC);
    float* h2all = alloc((size_t)BATCH * T * DEC);    // 3.9 MB, row = b*T+t

    // zero recurrent state each call (deterministic across graph replays)
    hipMemsetAsync(Xcat1, 0, (size_t)BATCH * KCAT1 * 4, stream);
    hipMemsetAsync(Xcat2, 0, (size_t)BATCH * KCAT2 * 4, stream);
    hipMemsetAsync(c1, 0, (size_t)BATCH * DEC * 4, stream);
    hipMemsetAsync(c2, 0, (size_t)BATCH * DEC * 4, stream);

    build_aux<<<256, 256, 0, stream>>>(b_ih1, b_hh1, bsum1, b_ih2, b_hh2, bsum2, W2, W2t);
    build_wcat<<<2048, 256, 0, stream>>>(W_ih1, W_hh1, Wcat1, W_ih2, W_hh2, Wcat2);
    gather_emb<<<(T * BATCH * EMBED) / 256, 256, 0, stream>>>(captions, emb, xg);
    // feat_W1 = features @ W1^T + b1 : [3136, 512]
    gemm64<<<dim3(ATT / 64, BATCH * P / 64), 256, 0, stream>>>(
        features, ENC, W1, ENC, fW1, ATT, b1, ATT, ENC);
    // xembb[t*B+b] = emb_t @ W_ih1[:, :256]^T + b_ih1 + b_hh1 : [1920, 2048]
    gemm64<<<dim3(G4 / 64, T * BATCH / 64), 256, 0, stream>>>(
        xg, EMBED, W_ih1, EMBED + ENC, xembb, G4, bsum1, G4, EMBED);

    for (int t = 0; t < T; ++t) {
        attn_fused<<<BATCH, 512, 0, stream>>>(Xcat2, W2t, b2, fW1, V, bV, features, Xcat1);
        // gates1 partials: [ctx|h1] @ Wcat1^T, K=2560 in 16 chunks of 160
        gemm64_splitk<<<dim3(G4 / 64, 16), 256, 0, stream>>>(
            Xcat1, KCAT1, Wcat1, KCAT1, Partb, G4, 160);
        lstm_point_reduce<<<BATCH * DEC / 256, 256, 0, stream>>>(
            Partb, 16, xembb + (size_t)t * BATCH * G4, G4, c1,
            Xcat1 + ENC, KCAT1, Xcat2, KCAT2);
        // gates2 partials: [h1n|h2] @ Wcat2^T, K=1024 in 16 chunks of 64
        gemm64_splitk<<<dim3(G4 / 64, 16), 256, 0, stream>>>(
            Xcat2, KCAT2, Wcat2, KCAT2, Partb, G4, 64);
        lstm_point_reduce<<<BATCH * DEC / 256, 256, 0, stream>>>(
            Partb, 16, bsum2, 0, c2,
            Xcat2 + DEC, KCAT2, h2all + (size_t)t * DEC, T * DEC);
    }
    // out = h2all @ fc_W^T + fc_b : [1920, 10000]
    gemm64<<<dim3((VOCAB + 63) / 64, T * BATCH / 64), 256, 0, stream>>>(
        h2all, DEC, fc_W, DEC, out, VOCAB, fc_b, VOCAB, DEC);
}